// Round 3
// baseline (347.743 us; speedup 1.0000x reference)
//
#include <hip/hip_runtime.h>

// QuantizedBottleneck via i8 MFMA implicit GEMM. Exact integer math.
//   prep : pack all MFMA A-fragments (w1/w2/w3 -> i8) into d_ws, coalesced reads later
//   conv1: 1x1 256->64 + bn1 -> t1 [n][64] i8 ; also stores ra8 = rescaled residual (int8)
//   conv2: 3x3 64->64 pad1 + bn2 -> t2 [n][64] i8 (4 rows/block, 6-row halo in LDS)
//   conv3: 1x1 64->256 + bn3 + residual add -> out int32
// t1/t2 hold (q - next_zin) so zero-padding == zero bytes.
// MFMA 16x16x64_i8: A[m=lane&15][k=(lane>>4)*16+j], B[k][n=lane&15],
// C/D: col=lane&15, row=(lane>>4)*4+reg.

typedef int v4i __attribute__((ext_vector_type(4)));

#define BATCH 32
#define CIN 256
#define CMID 64
#define HW 3136
#define W56 56

#define T1_BYTES ((size_t)BATCH * HW * CMID)      // 6,422,528
#define RA_BYTES ((size_t)BATCH * HW * CIN)       // 25,690,112
#define WP_BYTES ((size_t)68 * 64 * 16)           // 69,632
#define NEED_FULL (WP_BYTES + 2 * T1_BYTES + RA_BYTES)

__device__ __forceinline__ int requant_q(int acc, int M0, int shift, int zout) {
    long long prod = (long long)acc * (long long)M0;
    long long nudge = (prod >= 0) ? (1LL << 30) : (1LL - (1LL << 30));
    long long hi = (prod + nudge) >> 31;
    long long r = (hi + (1LL << (shift - 1))) >> shift;
    int v = (int)r + zout;
    return v < 0 ? 0 : (v > 255 ? 255 : v);
}

__device__ __forceinline__ long long mulshift_ll(long long v, int M0, int shift) {
    long long prod = v * (long long)M0;
    long long nudge = (prod >= 0) ? (1LL << 30) : (1LL - (1LL << 30));
    long long hi = (prod + nudge) >> 31;
    return (hi + (1LL << (shift - 1))) >> shift;
}

__device__ __forceinline__ v4i pack16f(const float* src, int stride) {
    v4i r;
#pragma unroll
    for (int d = 0; d < 4; ++d) {
        unsigned int u = 0;
#pragma unroll
        for (int by = 0; by < 4; ++by) {
            int v = (int)src[(d * 4 + by) * stride];
            u |= ((unsigned int)(v & 255)) << (8 * by);
        }
        r[d] = (int)u;
    }
    return r;
}

// -------- prep: pack all A-fragments once. fragsets: w1 [0,16), w2 [16,52), w3 [52,68)
__global__ __launch_bounds__(256) void k_prep(
    const float* __restrict__ w1, const float* __restrict__ w2,
    const float* __restrict__ w3, v4i* __restrict__ wp)
{
    int id = blockIdx.x * 256 + threadIdx.x;
    int fid = id >> 6, lane = id & 63;
    if (fid >= 68) return;
    int col = lane & 15, ci0 = (lane >> 4) * 16;
    const float* src;
    int stride;
    if (fid < 16) {
        int wv = fid >> 2, ks = fid & 3;
        src = w1 + (size_t)(wv * 16 + col) * 256 + ks * 64 + ci0;
        stride = 1;
    } else if (fid < 52) {
        int i = fid - 16, wv = i / 9, t = i - wv * 9;
        src = w2 + ((size_t)(wv * 16 + col) * 64 + ci0) * 9 + t;
        stride = 9;
    } else {
        int s = fid - 52;
        src = w3 + (size_t)(s * 16 + col) * 64 + ci0;
        stride = 1;
    }
    wp[fid * 64 + lane] = pack16f(src, stride);
}

// -------- conv1: 1x1 256->64 + bn1 -> t1; fused residual-rescale store (ra8) ------
// grid (784), block 256. n-tile = 128 pixels; 4 waves = 4 co-strips of 16.
__global__ __launch_bounds__(256) void k_conv1(
    const int* __restrict__ x, const v4i* __restrict__ wp1,
    const float* __restrict__ bn_w, const float* __restrict__ bn_b,
    const int* __restrict__ conv_zin, const int* __restrict__ conv_m0,
    const int* __restrict__ conv_shift, const int* __restrict__ conv_zout,
    const int* __restrict__ bn_m0, const int* __restrict__ bn_shift,
    const int* __restrict__ bn_zout,
    const int* __restrict__ add_z, const int* __restrict__ add_m0,
    const int* __restrict__ add_shift,
    signed char* __restrict__ ra8, const int use_ra,
    signed char* __restrict__ t1)
{
    __shared__ v4i sm[640];                       // 128 pixels x 80B
    const int tid = threadIdx.x, lane = tid & 63, wv = tid >> 6;
    const int col = lane & 15, koff = lane >> 4;
    const int nbase = blockIdx.x * 128;
    const int co0 = wv * 16;

    v4i a[4];
#pragma unroll
    for (int ks = 0; ks < 4; ++ks) a[ks] = wp1[(wv * 4 + ks) * 64 + lane];

    const int p = tid & 127, ch = tid >> 7;
    const int np = nbase + p;
    const int pb = np / HW, phw = np - pb * HW;
    const int zin = conv_zin[0];
    const int az0 = add_z[0], am0 = add_m0[0], ash0 = add_shift[0];

    unsigned int pk[8], pk2[8];
    {
        const size_t xb = ((size_t)pb * CIN + ch * 32) * HW + phw;
#pragma unroll
        for (int d = 0; d < 8; ++d) {
            unsigned int u = 0;
#pragma unroll
            for (int by = 0; by < 4; ++by) {
                size_t ix = xb + (size_t)(d * 4 + by) * HW;
                int v = x[ix];
                if (use_ra)
                    ra8[ix] = (signed char)(int)mulshift_ll((long long)(v - az0), am0, ash0);
                u |= ((unsigned int)((v - zin) & 255)) << (8 * by);
            }
            pk[d] = u;
        }
    }

    v4i acc[8];
#pragma unroll
    for (int i = 0; i < 8; ++i) acc[i] = (v4i){0, 0, 0, 0};

    for (int ks = 0; ks < 4; ++ks) {
        __syncthreads();                          // prior reads of sm done
        v4i* dst = &sm[p * 5 + ch * 2];
        v4i w0v, w1v;
        w0v[0] = (int)pk[0]; w0v[1] = (int)pk[1]; w0v[2] = (int)pk[2]; w0v[3] = (int)pk[3];
        w1v[0] = (int)pk[4]; w1v[1] = (int)pk[5]; w1v[2] = (int)pk[6]; w1v[3] = (int)pk[7];
        dst[0] = w0v; dst[1] = w1v;
        __syncthreads();
        if (ks < 3) {                             // prefetch next K-step across barrier
            const size_t xb = ((size_t)pb * CIN + (ks + 1) * 64 + ch * 32) * HW + phw;
#pragma unroll
            for (int d = 0; d < 8; ++d) {
                unsigned int u = 0;
#pragma unroll
                for (int by = 0; by < 4; ++by) {
                    size_t ix = xb + (size_t)(d * 4 + by) * HW;
                    int v = x[ix];
                    if (use_ra)
                        ra8[ix] = (signed char)(int)mulshift_ll((long long)(v - az0), am0, ash0);
                    u |= ((unsigned int)((v - zin) & 255)) << (8 * by);
                }
                pk2[d] = u;
            }
        }
#pragma unroll
        for (int nt = 0; nt < 8; ++nt) {
            v4i bf = sm[(nt * 16 + col) * 5 + koff];
            acc[nt] = __builtin_amdgcn_mfma_i32_16x16x64_i8(a[ks], bf, acc[nt], 0, 0, 0);
        }
        if (ks < 3) {
#pragma unroll
            for (int d = 0; d < 8; ++d) pk[d] = pk2[d];
        }
    }

    const int cm0 = conv_m0[0], csh = conv_shift[0], czo = conv_zout[0];
    const int bm0 = bn_m0[0], bsh = bn_shift[0], bzo = bn_zout[0];
    const int zin2 = conv_zin[1];
    const int rowb = koff * 4;
    int bw[4], bb[4];
#pragma unroll
    for (int r = 0; r < 4; ++r) {
        bw[r] = (int)bn_w[co0 + rowb + r];
        bb[r] = (int)bn_b[co0 + rowb + r];
    }
#pragma unroll
    for (int nt = 0; nt < 8; ++nt) {
        int n = nbase + nt * 16 + col;
        unsigned int pkd = 0;
#pragma unroll
        for (int r = 0; r < 4; ++r) {
            int q = requant_q(acc[nt][r], cm0, csh, czo);
            int a2 = (q - czo) * bw[r] + bb[r];
            int q2 = requant_q(a2, bm0, bsh, bzo);
            pkd |= ((unsigned int)((q2 - zin2) & 255)) << (8 * r);
        }
        *(unsigned int*)(t1 + (size_t)n * 64 + co0 + rowb) = pkd;
    }
}

// -------- conv2: 3x3 64->64 pad1 + bn2 -> t2. grid (14,32): 4 rows x batch -------
__global__ __launch_bounds__(256) void k_conv2(
    const signed char* __restrict__ t1, const v4i* __restrict__ wp2,
    const float* __restrict__ bn_w, const float* __restrict__ bn_b,
    const int* __restrict__ conv_zin, const int* __restrict__ conv_m0,
    const int* __restrict__ conv_shift, const int* __restrict__ conv_zout,
    const int* __restrict__ bn_m0, const int* __restrict__ bn_shift,
    const int* __restrict__ bn_zout, signed char* __restrict__ t2)
{
    __shared__ v4i sm[1680];                      // 336 pixels (6 halo rows) x 80B
    const int tid = threadIdx.x, lane = tid & 63, wv = tid >> 6;
    const int col = lane & 15, koff = lane >> 4;
    const int b = blockIdx.y;
    const int r0 = blockIdx.x * 4;
    const int co0 = wv * 16;

    v4i a[9];
#pragma unroll
    for (int t = 0; t < 9; ++t) a[t] = wp2[(wv * 9 + t) * 64 + lane];

    const v4i* t1v = (const v4i*)t1;
#pragma unroll
    for (int k = 0; k < 6; ++k) {
        int idx = tid + k * 256;
        if (idx < 1344) {
            int pixl = idx >> 2, part = idx & 3;
            int lrow = pixl / W56, gw = pixl - lrow * W56;
            int grow = r0 - 1 + lrow;
            v4i v = (v4i){0, 0, 0, 0};
            if ((unsigned)grow < 56u)
                v = t1v[((size_t)b * HW + grow * W56 + gw) * 4 + part];
            sm[pixl * 5 + part] = v;
        }
    }
    __syncthreads();

    int orow[14], wc[14];
#pragma unroll
    for (int nt = 0; nt < 14; ++nt) {
        int pix = nt * 16 + col;
        orow[nt] = pix / W56;
        wc[nt] = pix - orow[nt] * W56;
    }

    v4i acc[14];
#pragma unroll
    for (int i = 0; i < 14; ++i) acc[i] = (v4i){0, 0, 0, 0};

#pragma unroll
    for (int kh = 0; kh < 3; ++kh) {
#pragma unroll
        for (int kw = 0; kw < 3; ++kw) {
            v4i af = a[kh * 3 + kw];
#pragma unroll
            for (int nt = 0; nt < 14; ++nt) {
                int sr = orow[nt] + kh;           // halo row 0..5
                int sw = wc[nt] + kw - 1;
                bool valid = (unsigned)sw < 56u;
                v4i bf = sm[(sr * W56 + (valid ? sw : 0)) * 5 + koff];
                if (!valid) { bf[0] = 0; bf[1] = 0; bf[2] = 0; bf[3] = 0; }
                acc[nt] = __builtin_amdgcn_mfma_i32_16x16x64_i8(af, bf, acc[nt], 0, 0, 0);
            }
        }
    }

    const int cm0 = conv_m0[1], csh = conv_shift[1], czo = conv_zout[1];
    const int bm0 = bn_m0[1], bsh = bn_shift[1], bzo = bn_zout[1];
    const int zin3 = conv_zin[2];
    const int rowb = koff * 4;
    int bw[4], bb[4];
#pragma unroll
    for (int r = 0; r < 4; ++r) {
        bw[r] = (int)bn_w[co0 + rowb + r];
        bb[r] = (int)bn_b[co0 + rowb + r];
    }
#pragma unroll
    for (int nt = 0; nt < 14; ++nt) {
        int pix = nt * 16 + col;
        int n = b * HW + r0 * W56 + pix;
        unsigned int pkd = 0;
#pragma unroll
        for (int r = 0; r < 4; ++r) {
            int q = requant_q(acc[nt][r], cm0, csh, czo);
            int a2 = (q - czo) * bw[r] + bb[r];
            int q2 = requant_q(a2, bm0, bsh, bzo);
            pkd |= ((unsigned int)((q2 - zin3) & 255)) << (8 * r);
        }
        *(unsigned int*)(t2 + (size_t)n * 64 + co0 + rowb) = pkd;
    }
}

// -------- conv3: 1x1 64->256 + bn3 + residual -> out. grid (784,4) --------------
__global__ __launch_bounds__(256) void k_conv3(
    const signed char* __restrict__ t2, const v4i* __restrict__ wp3,
    const float* __restrict__ bn_w, const float* __restrict__ bn_b,
    const int* __restrict__ x, const signed char* __restrict__ ra8, const int use_ra,
    const int* __restrict__ conv_m0, const int* __restrict__ conv_shift,
    const int* __restrict__ conv_zout,
    const int* __restrict__ bn_m0, const int* __restrict__ bn_shift,
    const int* __restrict__ bn_zout,
    const int* __restrict__ add_z, const int* __restrict__ add_m0,
    const int* __restrict__ add_shift, const int* __restrict__ add_zout,
    int* __restrict__ out)
{
    __shared__ v4i sm[640];
    const int tid = threadIdx.x, lane = tid & 63, wv = tid >> 6;
    const int col = lane & 15, koff = lane >> 4;
    const int nbase = blockIdx.x * 128;
    const int co0 = blockIdx.y * 64 + wv * 16;

    v4i a = wp3[(blockIdx.y * 4 + wv) * 64 + lane];

    const v4i* t2v = (const v4i*)t2;
#pragma unroll
    for (int k = 0; k < 2; ++k) {
        int idx = tid + k * 256;
        int pixl = idx >> 2, part = idx & 3;
        sm[pixl * 5 + part] = t2v[(size_t)(nbase + pixl) * 4 + part];
    }
    __syncthreads();

    v4i acc[8];
#pragma unroll
    for (int i = 0; i < 8; ++i) acc[i] = (v4i){0, 0, 0, 0};
#pragma unroll
    for (int nt = 0; nt < 8; ++nt) {
        v4i bf = sm[(nt * 16 + col) * 5 + koff];
        acc[nt] = __builtin_amdgcn_mfma_i32_16x16x64_i8(a, bf, acc[nt], 0, 0, 0);
    }

    const int cm0 = conv_m0[2], csh = conv_shift[2], czo = conv_zout[2];
    const int bm0 = bn_m0[2], bsh = bn_shift[2], bzo = bn_zout[2];
    const int az0 = add_z[0], az1 = add_z[1];
    const int am0 = add_m0[0], am1 = add_m0[1];
    const int ash0 = add_shift[0], ash1 = add_shift[1];
    const int azout = add_zout[0];
    const int rowb = koff * 4;
    int bw[4], bb[4];
#pragma unroll
    for (int r = 0; r < 4; ++r) {
        bw[r] = (int)bn_w[co0 + rowb + r];
        bb[r] = (int)bn_b[co0 + rowb + r];
    }
#pragma unroll
    for (int nt = 0; nt < 8; ++nt) {
        int n = nbase + nt * 16 + col;
        int pb = n / HW, phw = n - pb * HW;
#pragma unroll
        for (int r = 0; r < 4; ++r) {
            int co = co0 + rowb + r;
            int q = requant_q(acc[nt][r], cm0, csh, czo);
            int a2 = (q - czo) * bw[r] + bb[r];
            int q2 = requant_q(a2, bm0, bsh, bzo);
            size_t ix = ((size_t)pb * CIN + co) * HW + phw;
            int rav;
            if (use_ra) rav = (int)ra8[ix];
            else rav = (int)mulshift_ll((long long)(x[ix] - az0), am0, ash0);
            long long rb = mulshift_ll((long long)(q2 - az1), am1, ash1);
            int res = rav + (int)rb + azout;
            res = res < 0 ? 0 : (res > 255 ? 255 : res);
            out[ix] = res;
        }
    }
}

extern "C" void kernel_launch(void* const* d_in, const int* in_sizes, int n_in,
                              void* d_out, int out_size, void* d_ws, size_t ws_size,
                              hipStream_t stream) {
    const int* x = (const int*)d_in[0];
    const float* w1 = (const float*)d_in[1];
    const float* w2 = (const float*)d_in[2];
    const float* w3 = (const float*)d_in[3];
    const float* bn1_w = (const float*)d_in[4];
    const float* bn1_b = (const float*)d_in[5];
    const float* bn2_w = (const float*)d_in[6];
    const float* bn2_b = (const float*)d_in[7];
    const float* bn3_w = (const float*)d_in[8];
    const float* bn3_b = (const float*)d_in[9];
    const int* conv_zin = (const int*)d_in[10];
    const int* conv_m0 = (const int*)d_in[11];
    const int* conv_shift = (const int*)d_in[12];
    const int* conv_zout = (const int*)d_in[13];
    const int* bn_m0 = (const int*)d_in[14];
    const int* bn_shift = (const int*)d_in[15];
    const int* bn_zout = (const int*)d_in[16];
    const int* add_z = (const int*)d_in[17];
    const int* add_m0 = (const int*)d_in[18];
    const int* add_shift = (const int*)d_in[19];
    const int* add_zout = (const int*)d_in[20];

    v4i* wp = (v4i*)d_ws;                               // 68*64 frags = 69,632 B
    signed char* t1 = (signed char*)d_ws + WP_BYTES;
    signed char* t2 = t1 + T1_BYTES;
    signed char* ra8 = t2 + T1_BYTES;
    const int use_ra = (ws_size >= NEED_FULL) ? 1 : 0;  // ws ~300MB observed; guard anyway

    const v4i* wp1 = wp;
    const v4i* wp2 = wp + 16 * 64;
    const v4i* wp3 = wp + 52 * 64;

    k_prep<<<dim3(17), dim3(256), 0, stream>>>(w1, w2, w3, wp);
    k_conv1<<<dim3(784), dim3(256), 0, stream>>>(x, wp1, bn1_w, bn1_b,
        conv_zin, conv_m0, conv_shift, conv_zout, bn_m0, bn_shift, bn_zout,
        add_z, add_m0, add_shift, ra8, use_ra, t1);
    k_conv2<<<dim3(14, 32), dim3(256), 0, stream>>>(t1, wp2, bn2_w, bn2_b,
        conv_zin, conv_m0, conv_shift, conv_zout, bn_m0, bn_shift, bn_zout, t2);
    k_conv3<<<dim3(784, 4), dim3(256), 0, stream>>>(t2, wp3, bn3_w, bn3_b,
        x, ra8, use_ra, conv_m0, conv_shift, conv_zout, bn_m0, bn_shift, bn_zout,
        add_z, add_m0, add_shift, add_zout, (int*)d_out);
}

// Round 4
// 276.391 us; speedup vs baseline: 1.2582x; 1.2582x over previous
//
#include <hip/hip_runtime.h>

// QuantizedBottleneck via i8 MFMA implicit GEMM. Exact integer math.
//   prep : pack all MFMA A-fragments (w1/w2/w3 -> i8) into d_ws
//   conv1: 1x1 256->64 + bn1 -> t1 [n][64] i8   (dwordx4 staging, reg dbuf)
//   conv2: 3x3 64->64 pad1 + bn2 -> t2 [n][64] i8 (4 rows/block, halo LDS)
//   conv3: 1x1 64->256 + bn3 + residual add -> out int32 (hoisted x loads)
// t1/t2 hold (q - next_zin) so zero-padding == zero bytes.
// MFMA 16x16x64_i8: A[m=lane&15][k=(lane>>4)*16+j], B[k][n=lane&15],
// C/D: col=lane&15, row=(lane>>4)*4+reg.

typedef int v4i __attribute__((ext_vector_type(4)));

#define BATCH 32
#define CIN 256
#define CMID 64
#define HW 3136
#define W56 56

#define T1_BYTES ((size_t)BATCH * HW * CMID)
#define WP_BYTES ((size_t)68 * 64 * 16)

__device__ __forceinline__ int requant_q(int acc, int M0, int shift, int zout) {
    long long prod = (long long)acc * (long long)M0;
    long long nudge = (prod >= 0) ? (1LL << 30) : (1LL - (1LL << 30));
    long long hi = (prod + nudge) >> 31;
    long long r = (hi + (1LL << (shift - 1))) >> shift;
    int v = (int)r + zout;
    return v < 0 ? 0 : (v > 255 ? 255 : v);
}

__device__ __forceinline__ long long mulshift_ll(long long v, int M0, int shift) {
    long long prod = v * (long long)M0;
    long long nudge = (prod >= 0) ? (1LL << 30) : (1LL - (1LL << 30));
    long long hi = (prod + nudge) >> 31;
    return (hi + (1LL << (shift - 1))) >> shift;
}

__device__ __forceinline__ v4i pack16f(const float* src, int stride) {
    v4i r;
#pragma unroll
    for (int d = 0; d < 4; ++d) {
        unsigned int u = 0;
#pragma unroll
        for (int by = 0; by < 4; ++by) {
            int v = (int)src[(d * 4 + by) * stride];
            u |= ((unsigned int)(v & 255)) << (8 * by);
        }
        r[d] = (int)u;
    }
    return r;
}

// -------- prep: fragsets w1 [0,16), w2 [16,52), w3 [52,68) -------------------
__global__ __launch_bounds__(256) void k_prep(
    const float* __restrict__ w1, const float* __restrict__ w2,
    const float* __restrict__ w3, v4i* __restrict__ wp)
{
    int id = blockIdx.x * 256 + threadIdx.x;
    int fid = id >> 6, lane = id & 63;
    if (fid >= 68) return;
    int col = lane & 15, ci0 = (lane >> 4) * 16;
    const float* src;
    int stride;
    if (fid < 16) {
        int wv = fid >> 2, ks = fid & 3;
        src = w1 + (size_t)(wv * 16 + col) * 256 + ks * 64 + ci0;
        stride = 1;
    } else if (fid < 52) {
        int i = fid - 16, wv = i / 9, t = i - wv * 9;
        src = w2 + ((size_t)(wv * 16 + col) * 64 + ci0) * 9 + t;
        stride = 9;
    } else {
        int s = fid - 52;
        src = w3 + (size_t)(s * 16 + col) * 64 + ci0;
        stride = 1;
    }
    wp[fid * 64 + lane] = pack16f(src, stride);
}

// -------- conv1: 1x1 256->64 + bn1 -> t1 ------------------------------------
// grid (28, 32): row-pair x batch; tile = 112 pixels (1 row-pair, one b).
// Staging: thread (cg=tid&7, q=tid>>3, active q<28) loads 8 int4 (4 px, 8 ci)
// per K-step, packs to i8, b64 LDS writes (conflict-free). Register dbuf.
__global__ __launch_bounds__(256, 4) void k_conv1(
    const int* __restrict__ x, const v4i* __restrict__ wp1,
    const float* __restrict__ bn_w, const float* __restrict__ bn_b,
    const int* __restrict__ conv_zin, const int* __restrict__ conv_m0,
    const int* __restrict__ conv_shift, const int* __restrict__ conv_zout,
    const int* __restrict__ bn_m0, const int* __restrict__ bn_shift,
    const int* __restrict__ bn_zout, signed char* __restrict__ t1)
{
    __shared__ v4i sm[560];                        // 112 px x 80 B
    const int tid = threadIdx.x, lane = tid & 63, wv = tid >> 6;
    const int col = lane & 15, koff = lane >> 4;
    const int b = blockIdx.y;
    const int hw0 = blockIdx.x * 112;
    const int co0 = wv * 16;

    v4i a[4];
#pragma unroll
    for (int ks = 0; ks < 4; ++ks) a[ks] = wp1[(wv * 4 + ks) * 64 + lane];

    const int cg = tid & 7, q = tid >> 3;
    const bool act = q < 28;
    const int zin = conv_zin[0];
    const int* xbase = x + (size_t)b * CIN * HW + hw0 + 4 * q;

    v4i xa[8], xa2[8];
    if (act) {
#pragma unroll
        for (int j = 0; j < 8; ++j)
            xa[j] = *(const v4i*)(xbase + (size_t)(cg * 8 + j) * HW);
    }

    v4i acc[7];
#pragma unroll
    for (int i = 0; i < 7; ++i) acc[i] = (v4i){0, 0, 0, 0};

    unsigned long long* smu = (unsigned long long*)sm;
#pragma unroll
    for (int ks = 0; ks < 4; ++ks) {
        if (ks) __syncthreads();                   // prior MFMA reads done
        if (act) {
#pragma unroll
            for (int p = 0; p < 4; ++p) {
                unsigned int lo = 0, hi = 0;
#pragma unroll
                for (int j = 0; j < 4; ++j) {
                    lo |= ((unsigned int)((xa[j][p] - zin) & 255)) << (8 * j);
                    hi |= ((unsigned int)((xa[j + 4][p] - zin) & 255)) << (8 * j);
                }
                smu[(q * 4 + p) * 10 + cg] = ((unsigned long long)hi << 32) | lo;
            }
        }
        __syncthreads();
        if (ks < 3 && act) {                       // prefetch next K-step
#pragma unroll
            for (int j = 0; j < 8; ++j)
                xa2[j] = *(const v4i*)(xbase + (size_t)((ks + 1) * 64 + cg * 8 + j) * HW);
        }
#pragma unroll
        for (int nt = 0; nt < 7; ++nt) {
            v4i bf = sm[(nt * 16 + col) * 5 + koff];
            acc[nt] = __builtin_amdgcn_mfma_i32_16x16x64_i8(a[ks], bf, acc[nt], 0, 0, 0);
        }
        if (ks < 3) {
#pragma unroll
            for (int j = 0; j < 8; ++j) xa[j] = xa2[j];
        }
    }

    const int cm0 = conv_m0[0], csh = conv_shift[0], czo = conv_zout[0];
    const int bm0 = bn_m0[0], bsh = bn_shift[0], bzo = bn_zout[0];
    const int zin2 = conv_zin[1];
    const int rowb = koff * 4;
    int bw[4], bb[4];
#pragma unroll
    for (int r = 0; r < 4; ++r) {
        bw[r] = (int)bn_w[co0 + rowb + r];
        bb[r] = (int)bn_b[co0 + rowb + r];
    }
#pragma unroll
    for (int nt = 0; nt < 7; ++nt) {
        int n = b * HW + hw0 + nt * 16 + col;
        unsigned int pkd = 0;
#pragma unroll
        for (int r = 0; r < 4; ++r) {
            int qv = requant_q(acc[nt][r], cm0, csh, czo);
            int a2 = (qv - czo) * bw[r] + bb[r];
            int q2 = requant_q(a2, bm0, bsh, bzo);
            pkd |= ((unsigned int)((q2 - zin2) & 255)) << (8 * r);
        }
        *(unsigned int*)(t1 + (size_t)n * 64 + co0 + rowb) = pkd;
    }
}

// -------- conv2: 3x3 64->64 pad1 + bn2 -> t2. grid (14,32) ------------------
__global__ __launch_bounds__(256) void k_conv2(
    const signed char* __restrict__ t1, const v4i* __restrict__ wp2,
    const float* __restrict__ bn_w, const float* __restrict__ bn_b,
    const int* __restrict__ conv_zin, const int* __restrict__ conv_m0,
    const int* __restrict__ conv_shift, const int* __restrict__ conv_zout,
    const int* __restrict__ bn_m0, const int* __restrict__ bn_shift,
    const int* __restrict__ bn_zout, signed char* __restrict__ t2)
{
    __shared__ v4i sm[1680];                      // 336 px (6 halo rows) x 80 B
    const int tid = threadIdx.x, lane = tid & 63, wv = tid >> 6;
    const int col = lane & 15, koff = lane >> 4;
    const int b = blockIdx.y;
    const int r0 = blockIdx.x * 4;
    const int co0 = wv * 16;

    v4i a[9];
#pragma unroll
    for (int t = 0; t < 9; ++t) a[t] = wp2[(wv * 9 + t) * 64 + lane];

    const v4i* t1v = (const v4i*)t1;
#pragma unroll
    for (int k = 0; k < 6; ++k) {
        int idx = tid + k * 256;
        if (idx < 1344) {
            int pixl = idx >> 2, part = idx & 3;
            int lrow = pixl / W56, gw = pixl - lrow * W56;
            int grow = r0 - 1 + lrow;
            v4i v = (v4i){0, 0, 0, 0};
            if ((unsigned)grow < 56u)
                v = t1v[((size_t)b * HW + grow * W56 + gw) * 4 + part];
            sm[pixl * 5 + part] = v;
        }
    }
    __syncthreads();

    int orow[14], wc[14];
#pragma unroll
    for (int nt = 0; nt < 14; ++nt) {
        int pix = nt * 16 + col;
        orow[nt] = pix / W56;
        wc[nt] = pix - orow[nt] * W56;
    }

    v4i acc[14];
#pragma unroll
    for (int i = 0; i < 14; ++i) acc[i] = (v4i){0, 0, 0, 0};

#pragma unroll
    for (int kh = 0; kh < 3; ++kh) {
#pragma unroll
        for (int kw = 0; kw < 3; ++kw) {
            v4i af = a[kh * 3 + kw];
#pragma unroll
            for (int nt = 0; nt < 14; ++nt) {
                int sr = orow[nt] + kh;
                int sw = wc[nt] + kw - 1;
                bool valid = (unsigned)sw < 56u;
                v4i bf = sm[(sr * W56 + (valid ? sw : 0)) * 5 + koff];
                if (!valid) { bf[0] = 0; bf[1] = 0; bf[2] = 0; bf[3] = 0; }
                acc[nt] = __builtin_amdgcn_mfma_i32_16x16x64_i8(af, bf, acc[nt], 0, 0, 0);
            }
        }
    }

    const int cm0 = conv_m0[1], csh = conv_shift[1], czo = conv_zout[1];
    const int bm0 = bn_m0[1], bsh = bn_shift[1], bzo = bn_zout[1];
    const int zin3 = conv_zin[2];
    const int rowb = koff * 4;
    int bw[4], bb[4];
#pragma unroll
    for (int r = 0; r < 4; ++r) {
        bw[r] = (int)bn_w[co0 + rowb + r];
        bb[r] = (int)bn_b[co0 + rowb + r];
    }
#pragma unroll
    for (int nt = 0; nt < 14; ++nt) {
        int pix = nt * 16 + col;
        int n = b * HW + r0 * W56 + pix;
        unsigned int pkd = 0;
#pragma unroll
        for (int r = 0; r < 4; ++r) {
            int qv = requant_q(acc[nt][r], cm0, csh, czo);
            int a2 = (qv - czo) * bw[r] + bb[r];
            int q2 = requant_q(a2, bm0, bsh, bzo);
            pkd |= ((unsigned int)((q2 - zin3) & 255)) << (8 * r);
        }
        *(unsigned int*)(t2 + (size_t)n * 64 + co0 + rowb) = pkd;
    }
}

// -------- conv3: 1x1 64->256 + bn3 + residual -> out. grid (784,4) ----------
__global__ __launch_bounds__(256, 4) void k_conv3(
    const signed char* __restrict__ t2, const v4i* __restrict__ wp3,
    const float* __restrict__ bn_w, const float* __restrict__ bn_b,
    const int* __restrict__ x,
    const int* __restrict__ conv_m0, const int* __restrict__ conv_shift,
    const int* __restrict__ conv_zout,
    const int* __restrict__ bn_m0, const int* __restrict__ bn_shift,
    const int* __restrict__ bn_zout,
    const int* __restrict__ add_z, const int* __restrict__ add_m0,
    const int* __restrict__ add_shift, const int* __restrict__ add_zout,
    int* __restrict__ out)
{
    __shared__ v4i sm[640];
    const int tid = threadIdx.x, lane = tid & 63, wv = tid >> 6;
    const int col = lane & 15, koff = lane >> 4;
    const int nbase = blockIdx.x * 128;
    const int co0 = blockIdx.y * 64 + wv * 16;
    const int rowb = koff * 4;

    v4i a = wp3[(blockIdx.y * 4 + wv) * 64 + lane];

    // hoist ALL residual x loads first (independent of everything else)
    int nn[8], pb[8], phw[8];
#pragma unroll
    for (int nt = 0; nt < 8; ++nt) {
        nn[nt] = nbase + nt * 16 + col;
        pb[nt] = nn[nt] / HW;
        phw[nt] = nn[nt] - pb[nt] * HW;
    }
    int xv[8][4];
#pragma unroll
    for (int nt = 0; nt < 8; ++nt)
#pragma unroll
        for (int r = 0; r < 4; ++r)
            xv[nt][r] = x[((size_t)pb[nt] * CIN + co0 + rowb + r) * HW + phw[nt]];

    const v4i* t2v = (const v4i*)t2;
#pragma unroll
    for (int k = 0; k < 2; ++k) {
        int idx = tid + k * 256;
        int pixl = idx >> 2, part = idx & 3;
        sm[pixl * 5 + part] = t2v[(size_t)(nbase + pixl) * 4 + part];
    }
    __syncthreads();

    v4i acc[8];
#pragma unroll
    for (int i = 0; i < 8; ++i) acc[i] = (v4i){0, 0, 0, 0};
#pragma unroll
    for (int nt = 0; nt < 8; ++nt) {
        v4i bf = sm[(nt * 16 + col) * 5 + koff];
        acc[nt] = __builtin_amdgcn_mfma_i32_16x16x64_i8(a, bf, acc[nt], 0, 0, 0);
    }

    const int cm0 = conv_m0[2], csh = conv_shift[2], czo = conv_zout[2];
    const int bm0 = bn_m0[2], bsh = bn_shift[2], bzo = bn_zout[2];
    const int az0 = add_z[0], az1 = add_z[1];
    const int am0 = add_m0[0], am1 = add_m0[1];
    const int ash0 = add_shift[0], ash1 = add_shift[1];
    const int azout = add_zout[0];
    int bw[4], bb[4];
#pragma unroll
    for (int r = 0; r < 4; ++r) {
        bw[r] = (int)bn_w[co0 + rowb + r];
        bb[r] = (int)bn_b[co0 + rowb + r];
    }
#pragma unroll
    for (int nt = 0; nt < 8; ++nt) {
#pragma unroll
        for (int r = 0; r < 4; ++r) {
            int qv = requant_q(acc[nt][r], cm0, csh, czo);
            int a2 = (qv - czo) * bw[r] + bb[r];
            int q2 = requant_q(a2, bm0, bsh, bzo);
            long long ra = mulshift_ll((long long)(xv[nt][r] - az0), am0, ash0);
            long long rb = mulshift_ll((long long)(q2 - az1), am1, ash1);
            int res = (int)(ra + rb) + azout;
            res = res < 0 ? 0 : (res > 255 ? 255 : res);
            out[((size_t)pb[nt] * CIN + co0 + rowb + r) * HW + phw[nt]] = res;
        }
    }
}

extern "C" void kernel_launch(void* const* d_in, const int* in_sizes, int n_in,
                              void* d_out, int out_size, void* d_ws, size_t ws_size,
                              hipStream_t stream) {
    const int* x = (const int*)d_in[0];
    const float* w1 = (const float*)d_in[1];
    const float* w2 = (const float*)d_in[2];
    const float* w3 = (const float*)d_in[3];
    const float* bn1_w = (const float*)d_in[4];
    const float* bn1_b = (const float*)d_in[5];
    const float* bn2_w = (const float*)d_in[6];
    const float* bn2_b = (const float*)d_in[7];
    const float* bn3_w = (const float*)d_in[8];
    const float* bn3_b = (const float*)d_in[9];
    const int* conv_zin = (const int*)d_in[10];
    const int* conv_m0 = (const int*)d_in[11];
    const int* conv_shift = (const int*)d_in[12];
    const int* conv_zout = (const int*)d_in[13];
    const int* bn_m0 = (const int*)d_in[14];
    const int* bn_shift = (const int*)d_in[15];
    const int* bn_zout = (const int*)d_in[16];
    const int* add_z = (const int*)d_in[17];
    const int* add_m0 = (const int*)d_in[18];
    const int* add_shift = (const int*)d_in[19];
    const int* add_zout = (const int*)d_in[20];

    v4i* wp = (v4i*)d_ws;
    signed char* t1 = (signed char*)d_ws + WP_BYTES;
    signed char* t2 = t1 + T1_BYTES;

    const v4i* wp1 = wp;
    const v4i* wp2 = wp + 16 * 64;
    const v4i* wp3 = wp + 52 * 64;

    k_prep<<<dim3(17), dim3(256), 0, stream>>>(w1, w2, w3, wp);
    k_conv1<<<dim3(28, 32), dim3(256), 0, stream>>>(x, wp1, bn1_w, bn1_b,
        conv_zin, conv_m0, conv_shift, conv_zout, bn_m0, bn_shift, bn_zout, t1);
    k_conv2<<<dim3(14, 32), dim3(256), 0, stream>>>(t1, wp2, bn2_w, bn2_b,
        conv_zin, conv_m0, conv_shift, conv_zout, bn_m0, bn_shift, bn_zout, t2);
    k_conv3<<<dim3(784, 4), dim3(256), 0, stream>>>(t2, wp3, bn3_w, bn3_b,
        x, conv_m0, conv_shift, conv_zout, bn_m0, bn_shift, bn_zout,
        add_z, add_m0, add_shift, add_zout, (int*)d_out);
}